// Round 5
// baseline (268.309 us; speedup 1.0000x reference)
//
#include <hip/hip_runtime.h>
#include <hip/hip_bf16.h>
#include <math.h>

#define BB 128   // batch
#define NN 96    // perturbations
#define DD 3072  // C*H*W
#define KK 10    // classes
#define SPL 8    // K-splits = waves per block in k1
#define KST 12   // MFMA K-steps per wave: 3072 / (SPL*32)

typedef short s16x8 __attribute__((ext_vector_type(8)));
typedef float f32x4 __attribute__((ext_vector_type(4)));

// ---------------- Kernel 0: pack W into B-fragment layout ----------------
__global__ __launch_bounds__(256) void k0_pack(
    const float* __restrict__ W, unsigned short* __restrict__ pwg,
    unsigned int* __restrict__ counter)
{
    if (blockIdx.x == 0 && threadIdx.x == 0) *counter = 0u;
    const int r = blockIdx.x * 256 + threadIdx.x;   // 0..6143
    const int col  = r & 15;
    const int quad = (r >> 4) & 3;
    const int kb   = r >> 6;
    union { unsigned short us[8]; uint4 v; } rec;
#pragma unroll
    for (int j = 0; j < 8; ++j) {
        const int k = kb * 32 + quad * 8 + j;
        const float v = (col < KK) ? W[k * KK + col] : 0.0f;
        const __hip_bfloat16 h = __float2bfloat16(v);
        __builtin_memcpy(&rec.us[j], &h, 2);
    }
    ((uint4*)pwg)[r] = rec.v;
}

// ---------------- Kernel 1: MFMA logits + per-(n,b) losses ----------------
// *** INSTRUMENTATION ROUND: K-loop executed TWICE via opaque pointers ***
// Pass 2 is bit-identical to pass 1 (same inputs, same order) -> acc2 == acc
// exactly; final (acc+acc2)*0.5f == acc exactly (x+x and *0.5 are exact).
// asm volatile on the pointers prevents CSE of the two passes. Delta of the
// bench total vs R4 measures k1's true duration (second pass re-streams
// deltas from HBM; per-block 196KB >> L2 share).
__global__ __launch_bounds__(512) void k1_mfma(
    const float* __restrict__ imgs,    // (128, 3072)
    const float* __restrict__ deltas,  // (96, 128, 3072)
    const unsigned short* __restrict__ pwg,
    const float* __restrict__ bias,    // (10)
    const int*   __restrict__ labels,  // (128)
    float* __restrict__ l1_ws,         // (128, 96)
    float* __restrict__ l2_ws)         // (128, 96)
{
    const int lane = threadIdx.x & 63;
    const int wv   = threadIdx.x >> 6;      // 0..7 = K-split
    const int tile = blockIdx.x;            // 0..767
    const int r0   = tile * 16;
    const int n    = r0 >> 7;               // constant over tile
    const int b0   = r0 & 127;
    const int m    = lane & 15;             // A row within tile
    const int quad = lane >> 4;

    const float* ap0 = deltas + (size_t)(r0 + m) * DD + wv * (KST * 32) + quad * 8;
    const float* ip0 = imgs   + (size_t)(b0 + m) * DD + wv * (KST * 32) + quad * 8;
    const unsigned short* wp0 = pwg + ((size_t)(wv * KST) * 64 + lane) * 8;

    // ---- pass 1 ----
    const float* ap = ap0;
    const float* ip = ip0;
    const unsigned short* wp = wp0;
    f32x4 acc = {0.f, 0.f, 0.f, 0.f};
#pragma unroll 2
    for (int s = 0; s < KST; ++s) {
        const float4 d0 = *(const float4*)(ap);
        const float4 d1 = *(const float4*)(ap + 4);
        const float4 i0 = *(const float4*)(ip);
        const float4 i1 = *(const float4*)(ip + 4);
        const s16x8 bfrag = *(const s16x8*)(wp);
        float x[8];
        x[0] = d0.x + i0.x; x[1] = d0.y + i0.y; x[2] = d0.z + i0.z; x[3] = d0.w + i0.w;
        x[4] = d1.x + i1.x; x[5] = d1.y + i1.y; x[6] = d1.z + i1.z; x[7] = d1.w + i1.w;
        s16x8 afrag;
#pragma unroll
        for (int j = 0; j < 8; ++j) {
            const float xc = fminf(fmaxf(x[j], 0.f), 1.f);
            const __hip_bfloat16 h = __float2bfloat16(xc);
            unsigned short us; __builtin_memcpy(&us, &h, 2);
            afrag[j] = (short)us;
        }
        acc = __builtin_amdgcn_mfma_f32_16x16x32_bf16(afrag, bfrag, acc, 0, 0, 0);
        ap += 32; ip += 32; wp += 512;
    }

    // ---- opaque second pass (compiler cannot prove it's the same data) ----
    const float* ap2 = ap0;
    const float* ip2 = ip0;
    const unsigned short* wp2 = wp0;
    asm volatile("" : "+v"(ap2), "+v"(ip2), "+v"(wp2));
    f32x4 acc2 = {0.f, 0.f, 0.f, 0.f};
#pragma unroll 2
    for (int s = 0; s < KST; ++s) {
        const float4 d0 = *(const float4*)(ap2);
        const float4 d1 = *(const float4*)(ap2 + 4);
        const float4 i0 = *(const float4*)(ip2);
        const float4 i1 = *(const float4*)(ip2 + 4);
        const s16x8 bfrag = *(const s16x8*)(wp2);
        float x[8];
        x[0] = d0.x + i0.x; x[1] = d0.y + i0.y; x[2] = d0.z + i0.z; x[3] = d0.w + i0.w;
        x[4] = d1.x + i1.x; x[5] = d1.y + i1.y; x[6] = d1.z + i1.z; x[7] = d1.w + i1.w;
        s16x8 afrag;
#pragma unroll
        for (int j = 0; j < 8; ++j) {
            const float xc = fminf(fmaxf(x[j], 0.f), 1.f);
            const __hip_bfloat16 h = __float2bfloat16(xc);
            unsigned short us; __builtin_memcpy(&us, &h, 2);
            afrag[j] = (short)us;
        }
        acc2 = __builtin_amdgcn_mfma_f32_16x16x32_bf16(afrag, bfrag, acc2, 0, 0, 0);
        ap2 += 32; ip2 += 32; wp2 += 512;
    }

    const f32x4 accf = (acc + acc2) * 0.5f;   // exact: acc2==acc bitwise

    // C layout (m89-verified): col = lane&15, row = quad*4 + reg.
    __shared__ float sred[SPL][16][16];     // 8 KB
#pragma unroll
    for (int reg = 0; reg < 4; ++reg)
        sred[wv][quad * 4 + reg][m] = accf[reg];
    __syncthreads();

    if (wv == 0 && lane < 16) {
        const int rr = lane;                // tile row -> b = b0+rr
        float lg[KK];
#pragma unroll
        for (int k = 0; k < KK; ++k) {
            float s = 0.f;
#pragma unroll
            for (int sp = 0; sp < SPL; ++sp) s += sred[sp][rr][k];
            lg[k] = s + bias[k];
        }
        // top-1 (first max -> lower index on ties, matches lax.top_k)
        int top1 = 0; float m1 = lg[0];
#pragma unroll
        for (int k = 1; k < KK; ++k) if (lg[k] > m1) { m1 = lg[k]; top1 = k; }
        int sec = (top1 == 0) ? 1 : 0; float m2 = lg[sec];
#pragma unroll
        for (int k = 0; k < KK; ++k)
            if (k != top1 && lg[k] > m2) { m2 = lg[k]; sec = k; }
        float se = 0.f;
#pragma unroll
        for (int k = 0; k < KK; ++k) se += expf(lg[k] - m1);
        const float lse = m1 + logf(se);
        const int b = b0 + rr;
        const int lab = labels[b];
        const float loss1 = lse - lg[lab];
        const float loss2 = (top1 == lab) ? (lse - lg[sec]) : -10000.0f;
        l1_ws[b * NN + n] = loss1;
        l2_ws[b * NN + n] = loss2;
    }
}

// ---------------- Kernel 2: per-b selection + fused final mean ----------------
__global__ __launch_bounds__(128) void k2_select(
    const float* __restrict__ l1_ws, const float* __restrict__ l2_ws,
    const int* __restrict__ ind_p, float* __restrict__ perb,
    unsigned int* __restrict__ counter, float* __restrict__ out)
{
    const int b = blockIdx.x;
    const int t = threadIdx.x;
    __shared__ float sd[NN];
    __shared__ float sl2[NN];
    __shared__ float ssel;
    __shared__ float swsum[2];
    __shared__ unsigned int slast;

    float myl1 = 0.f, myd = 0.f;
    if (t < NN) {
        const float a = l1_ws[b * NN + t];
        const float c = l2_ws[b * NN + t];
        myl1 = a; myd = a - c;
        sd[t] = myd; sl2[t] = c;
    }
    __syncthreads();

    if (t < NN) {
        int rank = 0;
        for (int j = 0; j < NN; ++j) {
            const float dj = sd[j];
            rank += (dj < myd) || (dj == myd && j < t);  // stable argsort
        }
        if (rank == ind_p[0]) ssel = sl2[t];
    }

    float s = myl1;
#pragma unroll
    for (int off = 32; off >= 1; off >>= 1) s += __shfl_down(s, off, 64);
    if ((t & 63) == 0) swsum[t >> 6] = s;
    __syncthreads();
    if (t == 0) {
        const float total = swsum[0] + swsum[1];
        perb[b] = total / 96.0f - ssel;
        __threadfence();                       // publish perb[b] device-wide
        const unsigned int prev = atomicAdd(counter, 1u);
        slast = (prev == BB - 1) ? 1u : 0u;    // am I the last block?
    }
    __syncthreads();

    if (slast) {
        __threadfence();                       // acquire other blocks' perb
        float v = perb[t];                     // t in 0..127
#pragma unroll
        for (int off = 32; off >= 1; off >>= 1) v += __shfl_down(v, off, 64);
        if ((t & 63) == 0) swsum[t >> 6] = v;
        __syncthreads();
        if (t == 0) out[0] = (swsum[0] + swsum[1]) / 128.0f;
    }
}

extern "C" void kernel_launch(void* const* d_in, const int* in_sizes, int n_in,
                              void* d_out, int out_size, void* d_ws, size_t ws_size,
                              hipStream_t stream) {
    const float* imgs   = (const float*)d_in[0];
    const float* deltas = (const float*)d_in[1];
    const float* W      = (const float*)d_in[2];
    const float* bias   = (const float*)d_in[3];
    const int*   labels = (const int*)d_in[4];
    const int*   ind    = (const int*)d_in[5];
    float* out = (float*)d_out;

    float* l1_ws = (float*)d_ws;                   // 12288 floats
    float* l2_ws = l1_ws + NN * BB;                // 12288 floats
    float* perb  = l2_ws + NN * BB;                // 128 floats
    unsigned int* counter = (unsigned int*)(perb + BB);  // 1 uint (zeroed in k0)
    unsigned short* pwg = (unsigned short*)(counter + 4); // 96 KB packed W (16B-aligned)

    k0_pack<<<dim3(24), dim3(256), 0, stream>>>(W, pwg, counter);
    k1_mfma<<<dim3(768), dim3(512), 0, stream>>>(
        imgs, deltas, pwg, bias, labels, l1_ws, l2_ws);
    k2_select<<<dim3(BB), dim3(128), 0, stream>>>(
        l1_ws, l2_ws, ind, perb, counter, out);
}

// Round 6
// 241.970 us; speedup vs baseline: 1.1089x; 1.1089x over previous
//
#include <hip/hip_runtime.h>
#include <hip/hip_bf16.h>
#include <math.h>

#define BB 128    // batch
#define NN 96     // perturbations
#define DD 3072   // C*H*W
#define KK 10     // classes
#define SPL 8     // waves per block in k1
#define W_CH 256  // floats of D per row per staged chunk
#define NCH 12    // 3072 / 256 chunks

typedef short s16x8 __attribute__((ext_vector_type(8)));
typedef float f32x4 __attribute__((ext_vector_type(4)));

// ---------------- Kernel 0: pack W into B-fragment layout ----------------
// Record r (0..6143): col=r&15, quad=(r>>4)&3, kb=r>>6. 16B record holds
// bf16 W[kb*32+quad*8+j][col], j=0..7 (zero for col>=10). Lane `l` of
// K-block kb then reads record kb*64+l with ONE coalesced dwordx4.
// Also zeroes the k2 completion counter (workspace is poisoned each iter).
__global__ __launch_bounds__(256) void k0_pack(
    const float* __restrict__ W, unsigned short* __restrict__ pwg,
    unsigned int* __restrict__ counter)
{
    if (blockIdx.x == 0 && threadIdx.x == 0) *counter = 0u;
    const int r = blockIdx.x * 256 + threadIdx.x;   // 0..6143
    const int col  = r & 15;
    const int quad = (r >> 4) & 3;
    const int kb   = r >> 6;
    union { unsigned short us[8]; uint4 v; } rec;
#pragma unroll
    for (int j = 0; j < 8; ++j) {
        const int k = kb * 32 + quad * 8 + j;
        const float v = (col < KK) ? W[k * KK + col] : 0.0f;
        const __hip_bfloat16 h = __float2bfloat16(v);
        __builtin_memcpy(&rec.us[j], &h, 2);
    }
    ((uint4*)pwg)[r] = rec.v;
}

// ---------------- Kernel 1: MFMA logits + per-(n,b) losses ----------------
// v4: LDS-staged deltas for DRAM stream locality. R5 measurement: k1 ~68us,
// MfmaUtil 0.9%, VALUBusy 4.3%, HBM 18.6%, FETCH minimal -> latency/stream
// bound, not issue/occupancy bound. Old fragment-direct loads = 16 rows x
// 128B per wave-step -> ~10K concurrent 128B-granule streams -> ~2.1 TB/s.
// New: each block's 16 deltas rows are staged in 12 chunks of 16KB; each
// wave loads 2 whole 1KB row-segments per chunk = fully contiguous per-instr
// streams. Double-buffered LDS (40KB/block -> 4 blocks/CU), T14 split
// (issue global loads early, ds_write after compute) so next chunk's HBM
// loads fly under current chunk's MFMA. Fragments then read from LDS.
// Wave wv now accumulates K-slices {c*256 + wv*32} (reassociation only;
// output dominated by exact -10000 sentinel => tolerance-safe).
__global__ __launch_bounds__(512) void k1_mfma(
    const float* __restrict__ imgs,    // (128, 3072)
    const float* __restrict__ deltas,  // (96, 128, 3072)
    const unsigned short* __restrict__ pwg,
    const float* __restrict__ bias,    // (10)
    const int*   __restrict__ labels,  // (128)
    float* __restrict__ l1_ws,         // (128, 96)
    float* __restrict__ l2_ws)         // (128, 96)
{
    const int lane = threadIdx.x & 63;
    const int wv   = threadIdx.x >> 6;      // 0..7
    const int tile = blockIdx.x;            // 0..767
    const int r0   = tile * 16;
    const int n    = r0 >> 7;               // constant over tile
    const int b0   = r0 & 127;
    const int m    = lane & 15;             // A row within tile
    const int quad = lane >> 4;

    __shared__ float ldsD[2][16][W_CH];     // 32 KB double-buffered deltas
    __shared__ float sred[SPL][16][16];     // 8 KB

    // -- staging identity: thread stages recs {wv*128+lane, +64} of each
    //    1024-rec chunk; rec -> (row=rec>>6, col16=rec&63). Per-wave, each
    //    of the 2 load instrs covers one contiguous 1KB row-segment.
    const int rec0  = wv * 128 + lane;
    const int rec1  = rec0 + 64;
    const int srow0 = rec0 >> 6, scol0 = rec0 & 63;  // col in 16B units
    const int srow1 = rec1 >> 6, scol1 = rec1 & 63;
    const float* gs0 = deltas + (size_t)(r0 + srow0) * DD + scol0 * 4;
    const float* gs1 = deltas + (size_t)(r0 + srow1) * DD + scol1 * 4;

    // -- compute identity: wave wv handles K-block kb = c*8 + wv
    const float* ipb = imgs + (size_t)(b0 + m) * DD + wv * 32 + quad * 8;
    const unsigned short* wpb = pwg + ((size_t)wv * 64 + lane) * 8;
    const int uf = wv * 32 + quad * 8;      // float offset in LDS row

    // -- prologue: stage chunk 0 into buf 0
    {
        const f32x4 s0 = *(const f32x4*)(gs0);
        const f32x4 s1 = *(const f32x4*)(gs1);
        *(f32x4*)&ldsD[0][srow0][scol0 * 4] = s0;
        *(f32x4*)&ldsD[0][srow1][scol1 * 4] = s1;
    }
    __syncthreads();

    f32x4 acc = {0.f, 0.f, 0.f, 0.f};
#pragma unroll 2
    for (int c = 0; c < NCH; ++c) {
        const int cb = c & 1;
        // T14 issue-early: next chunk's contiguous HBM loads
        f32x4 t0, t1;
        const bool more = (c + 1 < NCH);
        if (more) {
            t0 = *(const f32x4*)(gs0 + (c + 1) * W_CH);
            t1 = *(const f32x4*)(gs1 + (c + 1) * W_CH);
        }
        // compute chunk c from LDS
        const f32x4 dv0 = *(const f32x4*)&ldsD[cb][m][uf];
        const f32x4 dv1 = *(const f32x4*)&ldsD[cb][m][uf + 4];
        const f32x4 iv0 = *(const f32x4*)(ipb + c * W_CH);
        const f32x4 iv1 = *(const f32x4*)(ipb + c * W_CH + 4);
        const s16x8 bfrag = *(const s16x8*)(wpb + (size_t)c * 4096);
        s16x8 afrag;
#pragma unroll
        for (int j = 0; j < 4; ++j) {
            const float xc0 = fminf(fmaxf(dv0[j] + iv0[j], 0.f), 1.f);
            const float xc1 = fminf(fmaxf(dv1[j] + iv1[j], 0.f), 1.f);
            const __hip_bfloat16 h0 = __float2bfloat16(xc0);
            const __hip_bfloat16 h1 = __float2bfloat16(xc1);
            unsigned short us0, us1;
            __builtin_memcpy(&us0, &h0, 2);
            __builtin_memcpy(&us1, &h1, 2);
            afrag[j]     = (short)us0;
            afrag[j + 4] = (short)us1;
        }
        acc = __builtin_amdgcn_mfma_f32_16x16x32_bf16(afrag, bfrag, acc, 0, 0, 0);
        // T14 write-late: park next chunk in the other buffer
        if (more) {
            *(f32x4*)&ldsD[cb ^ 1][srow0][scol0 * 4] = t0;
            *(f32x4*)&ldsD[cb ^ 1][srow1][scol1 * 4] = t1;
        }
        __syncthreads();
    }

    // C layout (m89-verified): col = lane&15, row = quad*4 + reg.
#pragma unroll
    for (int reg = 0; reg < 4; ++reg)
        sred[wv][quad * 4 + reg][m] = acc[reg];
    __syncthreads();

    if (wv == 0 && lane < 16) {
        const int rr = lane;                // tile row -> b = b0+rr
        float lg[KK];
#pragma unroll
        for (int k = 0; k < KK; ++k) {
            float s = 0.f;
#pragma unroll
            for (int sp = 0; sp < SPL; ++sp) s += sred[sp][rr][k];
            lg[k] = s + bias[k];
        }
        // top-1 (first max -> lower index on ties, matches lax.top_k)
        int top1 = 0; float m1 = lg[0];
#pragma unroll
        for (int k = 1; k < KK; ++k) if (lg[k] > m1) { m1 = lg[k]; top1 = k; }
        int sec = (top1 == 0) ? 1 : 0; float m2 = lg[sec];
#pragma unroll
        for (int k = 0; k < KK; ++k)
            if (k != top1 && lg[k] > m2) { m2 = lg[k]; sec = k; }
        float se = 0.f;
#pragma unroll
        for (int k = 0; k < KK; ++k) se += expf(lg[k] - m1);
        const float lse = m1 + logf(se);
        const int b = b0 + rr;
        const int lab = labels[b];
        const float loss1 = lse - lg[lab];
        const float loss2 = (top1 == lab) ? (lse - lg[sec]) : -10000.0f;
        l1_ws[b * NN + n] = loss1;
        l2_ws[b * NN + n] = loss2;
    }
}

// ---------------- Kernel 2: per-b selection + fused final mean ----------------
__global__ __launch_bounds__(128) void k2_select(
    const float* __restrict__ l1_ws, const float* __restrict__ l2_ws,
    const int* __restrict__ ind_p, float* __restrict__ perb,
    unsigned int* __restrict__ counter, float* __restrict__ out)
{
    const int b = blockIdx.x;
    const int t = threadIdx.x;
    __shared__ float sd[NN];
    __shared__ float sl2[NN];
    __shared__ float ssel;
    __shared__ float swsum[2];
    __shared__ unsigned int slast;

    float myl1 = 0.f, myd = 0.f;
    if (t < NN) {
        const float a = l1_ws[b * NN + t];
        const float c = l2_ws[b * NN + t];
        myl1 = a; myd = a - c;
        sd[t] = myd; sl2[t] = c;
    }
    __syncthreads();

    if (t < NN) {
        int rank = 0;
        for (int j = 0; j < NN; ++j) {
            const float dj = sd[j];
            rank += (dj < myd) || (dj == myd && j < t);  // stable argsort
        }
        if (rank == ind_p[0]) ssel = sl2[t];
    }

    float s = myl1;
#pragma unroll
    for (int off = 32; off >= 1; off >>= 1) s += __shfl_down(s, off, 64);
    if ((t & 63) == 0) swsum[t >> 6] = s;
    __syncthreads();
    if (t == 0) {
        const float total = swsum[0] + swsum[1];
        perb[b] = total / 96.0f - ssel;
        __threadfence();                       // publish perb[b] device-wide
        const unsigned int prev = atomicAdd(counter, 1u);
        slast = (prev == BB - 1) ? 1u : 0u;    // am I the last block?
    }
    __syncthreads();

    if (slast) {
        __threadfence();                       // acquire other blocks' perb
        float v = perb[t];                     // t in 0..127
#pragma unroll
        for (int off = 32; off >= 1; off >>= 1) v += __shfl_down(v, off, 64);
        if ((t & 63) == 0) swsum[t >> 6] = v;
        __syncthreads();
        if (t == 0) out[0] = (swsum[0] + swsum[1]) / 128.0f;
    }
}

extern "C" void kernel_launch(void* const* d_in, const int* in_sizes, int n_in,
                              void* d_out, int out_size, void* d_ws, size_t ws_size,
                              hipStream_t stream) {
    const float* imgs   = (const float*)d_in[0];
    const float* deltas = (const float*)d_in[1];
    const float* W      = (const float*)d_in[2];
    const float* bias   = (const float*)d_in[3];
    const int*   labels = (const int*)d_in[4];
    const int*   ind    = (const int*)d_in[5];
    float* out = (float*)d_out;

    float* l1_ws = (float*)d_ws;                   // 12288 floats
    float* l2_ws = l1_ws + NN * BB;                // 12288 floats
    float* perb  = l2_ws + NN * BB;                // 128 floats
    unsigned int* counter = (unsigned int*)(perb + BB);  // 1 uint (zeroed in k0)
    unsigned short* pwg = (unsigned short*)(counter + 4); // 96 KB packed W (16B-aligned)

    k0_pack<<<dim3(24), dim3(256), 0, stream>>>(W, pwg, counter);
    k1_mfma<<<dim3(768), dim3(512), 0, stream>>>(
        imgs, deltas, pwg, bias, labels, l1_ws, l2_ws);
    k2_select<<<dim3(BB), dim3(128), 0, stream>>>(
        l1_ws, l2_ws, ind, perb, counter, out);
}